// Round 6
// baseline (430.154 us; speedup 1.0000x reference)
//
#include <hip/hip_runtime.h>

// Bahdanau attention fused kernel for MI355X (gfx950).
// scores[b][s] = softmax_s( v . tanh( hb[b,:] + enc[s,b,:] @ We ) )
// hb[b][n] = attn_b[n] + hidden[b,:] @ Wh   (exact f32, tiny)
// Big GEMM done in f16 MFMA (16x16x32), f32 accumulate.
// R5: NO LDS / NO barriers in the main loop. W pre-tiled into exact B-fragment
//     layout (L2-resident); A-frags loaded global->reg (L1-shared across the
//     4 waves) + f32->f16 cvt. 8 fully independent waves/CU hide each other's
//     load latency under MFMA.

typedef _Float16 f16;
typedef _Float16 half8 __attribute__((ext_vector_type(8)));
typedef float f32x4 __attribute__((ext_vector_type(4)));

#define KDIM 1024
#define NDIM 1024
#define SEQ  2048
#define NB   32

// ---------------------------------------------------------------------------
// prep_w: transpose + f16-convert the enc-half of attn_w into fragment layout:
// wt[ks][n][kgrp][j] = W[1024 + ks*32 + kgrp*8 + j][n]   (f16)
// (ks=0..31, n=0..1023, kgrp=0..3, j=0..7) -> linear offset g*8, g=(ks,n,kgrp)
// B-frag read in fused kernel: lane l, frag nj: 16B at
//   ks*32768 + (nslice + nj*16 + (l&15))*32 + (l>>4)*8   (f16 units)
// ---------------------------------------------------------------------------
__global__ __launch_bounds__(256) void prep_w(const float* __restrict__ w,
                                              f16* __restrict__ wt) {
    int g    = blockIdx.x * 256 + threadIdx.x;   // 0..131071
    int ks   = g >> 12;
    int rest = g & 4095;
    int n    = rest >> 2;
    int kgrp = rest & 3;
    int kbase = 1024 + ks * 32 + kgrp * 8;
    half8 h;
#pragma unroll
    for (int j = 0; j < 8; ++j)
        h[j] = (f16)w[(size_t)(kbase + j) * 1024 + n];
    *(half8*)&wt[(size_t)g * 8] = h;
}

// ---------------------------------------------------------------------------
// prep_hb: hb[b][n] = attn_b[n] + sum_k hidden[b][k] * attn_w[k][n]  (f32)
// ---------------------------------------------------------------------------
__global__ __launch_bounds__(256) void prep_hb(const float* __restrict__ hidden,
                                               const float* __restrict__ attn_w,
                                               const float* __restrict__ attn_b,
                                               float* __restrict__ hb) {
    int b = blockIdx.x >> 2;
    int n = (blockIdx.x & 3) * 256 + threadIdx.x;
    const float* h = hidden + (size_t)b * 1024;
    float acc = attn_b[n];
#pragma unroll 8
    for (int k = 0; k < 1024; ++k)
        acc += h[k] * attn_w[(size_t)k * 1024 + n];
    hb[(size_t)b * 1024 + n] = acc;
}

// ---------------------------------------------------------------------------
// fused_energy: per wg 64 flat rows of enc; 2 N-passes of 512.
// 4 waves, wave tile 64x128 (wave wv owns N-slice wv*128..wv*128+127).
// Per K-step (BK=32): 8 B-frag loads (f16, L2), 8 A f32 loads (L1) + cvt,
// 32 MFMA. No LDS, no barriers until the final score reduction.
// ---------------------------------------------------------------------------
__global__ __launch_bounds__(256, 2)
void fused_energy(const float* __restrict__ enc, const f16* __restrict__ wt,
                  const float* __restrict__ hb, const float* __restrict__ vvec,
                  float* __restrict__ out) {
    __shared__ float red[4][64];      // final cross-wave score partials only

    const int tid  = threadIdx.x;
    const int lane = tid & 63;
    const int wv   = tid >> 6;     // 0..3 = N-slice
    const int l15  = lane & 15;
    const int l4   = lane >> 4;
    const int wgrow = blockIdx.x * 64;

    // A-frag pointers: lane reads enc[(wgrow+mi*16+l15)*1024 + ks*32 + l4*8]
    const float* aP0 = enc + (size_t)(wgrow +  0 + l15) * KDIM + l4 * 8;
    const float* aP1 = enc + (size_t)(wgrow + 16 + l15) * KDIM + l4 * 8;
    const float* aP2 = enc + (size_t)(wgrow + 32 + l15) * KDIM + l4 * 8;
    const float* aP3 = enc + (size_t)(wgrow + 48 + l15) * KDIM + l4 * 8;

    // B-frag base (f16 units): + pass*512*32 + ks*32768 + nj*512
    const f16* bP = wt + (size_t)(wv * 128 + l15) * 32 + l4 * 8;

    float part[4][4];
#pragma unroll
    for (int mi = 0; mi < 4; ++mi)
#pragma unroll
        for (int rg = 0; rg < 4; ++rg) part[mi][rg] = 0.f;

    const f32x4 zero = {0.f, 0.f, 0.f, 0.f};

    for (int pass = 0; pass < 2; ++pass) {
        const f16* bPp = bP + (size_t)pass * 512 * 32;
        f32x4 acc[4][8];
#pragma unroll
        for (int mi = 0; mi < 4; ++mi)
#pragma unroll
            for (int nj = 0; nj < 8; ++nj) acc[mi][nj] = zero;

        for (int ks = 0; ks < 32; ++ks) {
            // ---- B fragments: 8x global_load_dwordx4 from L2-resident wt ----
            half8 bf[8];
            {
                const f16* bk = bPp + (size_t)ks * 32768;
#pragma unroll
                for (int nj = 0; nj < 8; ++nj)
                    bf[nj] = *(const half8*)(bk + nj * 512);
            }
            // ---- A fragments: 8x f32x4 from L1 (shared across waves) ----
            f32x4 a0[4], a1[4];
            a0[0] = *(const f32x4*)(aP0 + ks * 32);
            a1[0] = *(const f32x4*)(aP0 + ks * 32 + 4);
            a0[1] = *(const f32x4*)(aP1 + ks * 32);
            a1[1] = *(const f32x4*)(aP1 + ks * 32 + 4);
            a0[2] = *(const f32x4*)(aP2 + ks * 32);
            a1[2] = *(const f32x4*)(aP2 + ks * 32 + 4);
            a0[3] = *(const f32x4*)(aP3 + ks * 32);
            a1[3] = *(const f32x4*)(aP3 + ks * 32 + 4);
            half8 af[4];
#pragma unroll
            for (int mi = 0; mi < 4; ++mi)
#pragma unroll
                for (int j = 0; j < 4; ++j) {
                    af[mi][j]     = (f16)a0[mi][j];
                    af[mi][4 + j] = (f16)a1[mi][j];
                }
            // ---- 32 MFMA, nj-outer so bf[0..3] needed first ----
            __builtin_amdgcn_s_setprio(1);
#pragma unroll
            for (int nj = 0; nj < 8; ++nj)
#pragma unroll
                for (int mi = 0; mi < 4; ++mi)
                    acc[mi][nj] = __builtin_amdgcn_mfma_f32_16x16x32_f16(
                        af[mi], bf[nj], acc[mi][nj], 0, 0, 0);
            __builtin_amdgcn_s_setprio(0);
        }

        // epilogue: e = acc + hb -> tanh -> * v, accumulate per-row partials
        const int nbase = pass * 512 + wv * 128;
        float vv[8];
#pragma unroll
        for (int nj = 0; nj < 8; ++nj) vv[nj] = vvec[nbase + nj * 16 + l15];
#pragma unroll
        for (int mi = 0; mi < 4; ++mi) {
#pragma unroll
            for (int rg = 0; rg < 4; ++rg) {
                int rl = mi * 16 + l4 * 4 + rg;          // local row 0..63
                const float* hbrow = hb + (size_t)(rl & 31) * NDIM + nbase + l15;
                float sum = 0.f;
#pragma unroll
                for (int nj = 0; nj < 8; ++nj) {
                    float e  = acc[mi][nj][rg] + hbrow[nj * 16];
                    float e2 = __expf(2.f * e);
                    float th = 1.f - 2.f / (e2 + 1.f);   // tanh(e)
                    sum += th * vv[nj];
                }
                part[mi][rg] += sum;
            }
        }
    }

    // reduce over the 16 lanes holding different n-columns of the same row
#pragma unroll
    for (int mi = 0; mi < 4; ++mi) {
#pragma unroll
        for (int rg = 0; rg < 4; ++rg) {
            float p = part[mi][rg];
            p += __shfl_xor(p, 1);
            p += __shfl_xor(p, 2);
            p += __shfl_xor(p, 4);
            p += __shfl_xor(p, 8);
            if (l15 == 0) red[wv][mi * 16 + l4 * 4 + rg] = p;
        }
    }
    __syncthreads();
    if (tid < 64) {
        float s = red[0][tid] + red[1][tid] + red[2][tid] + red[3][tid];
        int rG = wgrow + tid;                  // flat row = s*32 + b
        out[(size_t)(rG & 31) * SEQ + (rG >> 5)] = s;   // raw score -> out[b][s]
    }
}

// ---------------------------------------------------------------------------
// softmax over S=2048 per batch row, in-place on out
// ---------------------------------------------------------------------------
__global__ __launch_bounds__(256) void softmax_rows(float* __restrict__ out) {
    const int b = blockIdx.x;
    float* row = out + (size_t)b * SEQ;
    const int tid  = threadIdx.x;
    const int lane = tid & 63;
    const int wv   = tid >> 6;
    __shared__ float sred[4];
    __shared__ float ssum[4];
    float x[8];
    float mx = -3.4e38f;
#pragma unroll
    for (int j = 0; j < 8; ++j) { x[j] = row[tid + j * 256]; mx = fmaxf(mx, x[j]); }
#pragma unroll
    for (int o = 1; o < 64; o <<= 1) mx = fmaxf(mx, __shfl_xor(mx, o));
    if (lane == 0) sred[wv] = mx;
    __syncthreads();
    mx = fmaxf(fmaxf(sred[0], sred[1]), fmaxf(sred[2], sred[3]));
    float s = 0.f;
#pragma unroll
    for (int j = 0; j < 8; ++j) { x[j] = __expf(x[j] - mx); s += x[j]; }
#pragma unroll
    for (int o = 1; o < 64; o <<= 1) s += __shfl_xor(s, o);
    if (lane == 0) ssum[wv] = s;
    __syncthreads();
    s = ssum[0] + ssum[1] + ssum[2] + ssum[3];
    float inv = 1.f / s;
#pragma unroll
    for (int j = 0; j < 8; ++j) row[tid + j * 256] = x[j] * inv;
}

extern "C" void kernel_launch(void* const* d_in, const int* in_sizes, int n_in,
                              void* d_out, int out_size, void* d_ws, size_t ws_size,
                              hipStream_t stream) {
    const float* hidden = (const float*)d_in[0];   // [32][1024]
    const float* enc    = (const float*)d_in[1];   // [2048][32][1024]
    const float* attn_w = (const float*)d_in[2];   // [2048][1024]
    const float* attn_b = (const float*)d_in[3];   // [1024]
    const float* v      = (const float*)d_in[4];   // [1024]
    float* out = (float*)d_out;                    // [32][2048]

    f16*   wt = (f16*)d_ws;                        // 2 MB fragment-tiled We
    float* hb = (float*)((char*)d_ws + (2u << 20)); // 128 KB

    prep_w<<<512, 256, 0, stream>>>(attn_w, wt);
    prep_hb<<<128, 256, 0, stream>>>(hidden, attn_w, attn_b, hb);
    fused_energy<<<1024, 256, 0, stream>>>(enc, wt, hb, v, out);
    softmax_rows<<<32, 256, 0, stream>>>(out);
}

// Round 7
// 313.277 us; speedup vs baseline: 1.3731x; 1.3731x over previous
//
#include <hip/hip_runtime.h>

// Bahdanau attention fused kernel for MI355X (gfx950).
// scores[b][s] = softmax_s( v . tanh( hb[b,:] + enc[s,b,:] @ We ) )
// R6: 256x256 tile, BK=32, 4-deep LDS ring, prefetch distance 2, raw
//     s_barrier + counted vmcnt(6) (T3/T4), one barrier per K-step.
//     N-split across blocks (4 slices) -> partials in ws -> softmax sums.

typedef _Float16 f16;
typedef _Float16 half8 __attribute__((ext_vector_type(8)));
typedef float f32x4 __attribute__((ext_vector_type(4)));

#define KDIM 1024
#define SEQ  2048
#define MROWS 65536

typedef __attribute__((address_space(1))) void gvoid;
typedef __attribute__((address_space(3))) void svoid;

__device__ __forceinline__ void gload_lds16(const void* g, void* l) {
    __builtin_amdgcn_global_load_lds((const gvoid*)g, (svoid*)l, 16, 0, 0);
}

// ---------------------------------------------------------------------------
// prep_w: transpose + f16-convert enc-half of attn_w into per-(nq,ks) tiles.
// Tile (nq*32+ks) = LDS image of [256 n][32 k]: 16B block
// p = nloc*4 + ((kblk + (nloc>>1)) & 3), payload k = ks*32 + kblk*8 + j.
// ---------------------------------------------------------------------------
__global__ __launch_bounds__(256) void prep_w(const float* __restrict__ w,
                                              f16* __restrict__ wt) {
    int idx  = blockIdx.x * 256 + threadIdx.x;   // 0..131071
    int kblk = idx & 3;
    int nloc = (idx >> 2) & 255;
    int tile = idx >> 10;                        // nq*32+ks, 0..127
    int nq   = tile >> 5, ks = tile & 31;
    int n_g  = nq * 256 + nloc;
    int kbase = 1024 + ks * 32 + kblk * 8;
    half8 h;
#pragma unroll
    for (int j = 0; j < 8; ++j)
        h[j] = (f16)w[(size_t)(kbase + j) * 1024 + n_g];
    int p = nloc * 4 + ((kblk + (nloc >> 1)) & 3);
    *(half8*)&wt[(size_t)tile * 8192 + p * 8] = h;
}

// ---------------------------------------------------------------------------
// prep_hb: hb[b][n] = attn_b[n] + sum_k hidden[b][k] * attn_w[k][n]  (f32)
// ---------------------------------------------------------------------------
__global__ __launch_bounds__(256) void prep_hb(const float* __restrict__ hidden,
                                               const float* __restrict__ attn_w,
                                               const float* __restrict__ attn_b,
                                               float* __restrict__ hb) {
    int b = blockIdx.x >> 2;
    int n = (blockIdx.x & 3) * 256 + threadIdx.x;
    const float* h = hidden + (size_t)b * 1024;
    float acc = attn_b[n];
#pragma unroll 8
    for (int k = 0; k < 1024; ++k)
        acc += h[k] * attn_w[(size_t)k * 1024 + n];
    hb[(size_t)b * 1024 + n] = acc;
}

// ---------------------------------------------------------------------------
// fused_energy: block = 256 flat rows x 256-wide N slice (nq). 8 waves 2Mx4N,
// wave tile 128x64, frags 8(M)x4(N), acc 128 f32. K-loop: 32 iters of BK=32.
// Pipeline: issue stage(t+2); vmcnt(6); cvt+ds_write A(t+1); compute(t);
// lgkmcnt(0); s_barrier.  Never vmcnt(0) until the tail.
// ---------------------------------------------------------------------------
__global__ __launch_bounds__(512, 2)
void fused_energy(const float* __restrict__ enc, const f16* __restrict__ wt,
                  const float* __restrict__ hb, const float* __restrict__ vvec,
                  float* __restrict__ partout) {
    __shared__ f16 Ws[4][8192];    // 4 x 16 KB W ring
    __shared__ f16 As[4][8192];    // 4 x 16 KB A ring
    __shared__ float red[4][256];  // 4 KB score partials

    const int tid  = threadIdx.x;
    const int lane = tid & 63;
    const int wv   = tid >> 6;          // 0..7
    const int wm   = wv >> 2;           // 0..1
    const int wn   = wv & 3;            // 0..3
    const int l15  = lane & 15;
    const int l4   = lane >> 4;

    // XCD-bijective block mapping: xcd x owns row-tiles x*32..x*32+31, all 4 nq
    const int bid   = blockIdx.x;       // 0..1023
    const int xcd   = bid & 7;
    const int chunk = bid >> 3;         // 0..127
    const int mt    = xcd * 32 + (chunk >> 2);
    const int nq    = chunk & 3;
    const int mrow0 = mt * 256;
    const int ncol0 = nq * 256;

    const char* wtNq = (const char*)wt + (size_t)nq * 32 * 16384;

    // A staging: thread -> (row ar, k-half akp); 16 f32 -> 16 f16 -> 2 ds_write
    const int ar  = tid >> 1;           // 0..255
    const int akp = tid & 1;
    const float* aG = enc + (size_t)(mrow0 + ar) * KDIM + akp * 16;
    const int kb0 = akp * 2;
    const int p0  = ar * 4 + ((kb0 + (ar >> 1)) & 3);
    const int p1  = ar * 4 + ((kb0 + 1 + (ar >> 1)) & 3);

    // W staging: wave wv owns 2 x 1KB segments
    const int wOff = wv * 2048 + lane * 16;

    char* const WsB = (char*)&Ws[0][0];
    char* const AsB = (char*)&As[0][0];

    int aOffB[8], bOffB[4];
#pragma unroll
    for (int mi = 0; mi < 8; ++mi) {
        int r = wm * 128 + mi * 16 + l15;
        aOffB[mi] = (r * 4 + ((l4 + (r >> 1)) & 3)) * 16;
    }
#pragma unroll
    for (int nj = 0; nj < 4; ++nj) {
        int n = wn * 64 + nj * 16 + l15;
        bOffB[nj] = (n * 4 + ((l4 + (n >> 1)) & 3)) * 16;
    }

    const f32x4 zero = {0.f, 0.f, 0.f, 0.f};
    f32x4 acc[8][4];
#pragma unroll
    for (int mi = 0; mi < 8; ++mi)
#pragma unroll
        for (int nj = 0; nj < 4; ++nj) acc[mi][nj] = zero;

    f32x4 aE[4], aO[4];   // A-load regs, parity by tile index

#define STAGE_W(TT)                                                          \
    {                                                                        \
        const char* ws_ = wtNq + (size_t)(TT) * 16384 + wOff;                \
        char* wd_ = WsB + ((TT) & 3) * 16384 + wOff;                         \
        gload_lds16(ws_, wd_);                                               \
        gload_lds16(ws_ + 1024, wd_ + 1024);                                 \
    }
#define LOAD_A(TT, R)                                                        \
    {                                                                        \
        const float* p_ = aG + (TT) * 32;                                    \
        R[0] = *(const f32x4*)(p_);     R[1] = *(const f32x4*)(p_ + 4);      \
        R[2] = *(const f32x4*)(p_ + 8); R[3] = *(const f32x4*)(p_ + 12);     \
    }
#define WRITE_A(TT, R)                                                       \
    {                                                                        \
        half8 h0_, h1_;                                                      \
        _Pragma("unroll") for (int j = 0; j < 4; ++j) {                      \
            h0_[j] = (f16)R[0][j]; h0_[4 + j] = (f16)R[1][j];                \
            h1_[j] = (f16)R[2][j]; h1_[4 + j] = (f16)R[3][j];                \
        }                                                                    \
        char* ab_ = AsB + ((TT) & 3) * 16384;                                \
        *(half8*)(ab_ + p0 * 16) = h0_;                                      \
        *(half8*)(ab_ + p1 * 16) = h1_;                                      \
    }
#define COMPUTE(TT)                                                          \
    {                                                                        \
        const char* wb_ = WsB + ((TT) & 3) * 16384;                          \
        const char* ab_ = AsB + ((TT) & 3) * 16384;                          \
        half8 bf_[4];                                                        \
        _Pragma("unroll") for (int nj = 0; nj < 4; ++nj)                     \
            bf_[nj] = *(const half8*)(wb_ + bOffB[nj]);                      \
        __builtin_amdgcn_s_setprio(1);                                       \
        _Pragma("unroll") for (int mi = 0; mi < 8; ++mi) {                   \
            half8 af_ = *(const half8*)(ab_ + aOffB[mi]);                    \
            _Pragma("unroll") for (int nj = 0; nj < 4; ++nj)                 \
                acc[mi][nj] = __builtin_amdgcn_mfma_f32_16x16x32_f16(        \
                    af_, bf_[nj], acc[mi][nj], 0, 0, 0);                     \
        }                                                                    \
        __builtin_amdgcn_s_setprio(0);                                       \
    }

    // ---- prologue: stage tiles 0,1; write A(0) ----
    STAGE_W(0); LOAD_A(0, aE);
    STAGE_W(1); LOAD_A(1, aO);
    asm volatile("s_waitcnt vmcnt(6)" ::: "memory");   // W0 + A0 done
    WRITE_A(0, aE);
    asm volatile("s_waitcnt lgkmcnt(0)" ::: "memory");
    __builtin_amdgcn_s_barrier();

    // ---- main loop: t = 0..29, unroll 2 for A-reg parity ----
    for (int t = 0; t < 30; t += 2) {
        STAGE_W(t + 2); LOAD_A(t + 2, aE);
        asm volatile("s_waitcnt vmcnt(6)" ::: "memory");  // iter t-1's 6 done
        WRITE_A(t + 1, aO);
        COMPUTE(t);
        asm volatile("s_waitcnt lgkmcnt(0)" ::: "memory");
        __builtin_amdgcn_s_barrier();

        STAGE_W(t + 3); LOAD_A(t + 3, aO);
        asm volatile("s_waitcnt vmcnt(6)" ::: "memory");
        WRITE_A(t + 2, aE);
        COMPUTE(t + 1);
        asm volatile("s_waitcnt lgkmcnt(0)" ::: "memory");
        __builtin_amdgcn_s_barrier();
    }
    // ---- tail: t = 30, 31 (tiles 30,31 staged; A(31) in aO) ----
    asm volatile("s_waitcnt vmcnt(0)" ::: "memory");      // A(31), W(31) done
    WRITE_A(31, aO);
    COMPUTE(30);
    asm volatile("s_waitcnt lgkmcnt(0)" ::: "memory");
    __builtin_amdgcn_s_barrier();
    COMPUTE(31);

#undef STAGE_W
#undef LOAD_A
#undef WRITE_A
#undef COMPUTE

    // ---- epilogue: e = acc + hb -> tanh -> * v, partial over this N slice ----
    float vv[4];
#pragma unroll
    for (int nj = 0; nj < 4; ++nj) vv[nj] = vvec[ncol0 + wn * 64 + nj * 16 + l15];
#pragma unroll
    for (int mi = 0; mi < 8; ++mi) {
#pragma unroll
        for (int rg = 0; rg < 4; ++rg) {
            int rl = wm * 128 + mi * 16 + l4 * 4 + rg;    // local row 0..255
            const float* hbrow = hb + (size_t)((mrow0 + rl) & 31) * 1024
                                 + ncol0 + wn * 64 + l15;
            float sum = 0.f;
#pragma unroll
            for (int nj = 0; nj < 4; ++nj) {
                float e  = acc[mi][nj][rg] + hbrow[nj * 16];
                float e2 = __expf(2.f * e);
                sum += (1.f - 2.f / (e2 + 1.f)) * vv[nj];  // tanh(e) * v
            }
            float p = sum;
            p += __shfl_xor(p, 1);
            p += __shfl_xor(p, 2);
            p += __shfl_xor(p, 4);
            p += __shfl_xor(p, 8);
            if (l15 == 0) red[wn][rl] = p;
        }
    }
    __syncthreads();
    if (tid < 256) {
        float s = red[0][tid] + red[1][tid] + red[2][tid] + red[3][tid];
        partout[(size_t)nq * MROWS + mrow0 + tid] = s;
    }
}

// ---------------------------------------------------------------------------
// softmax over S=2048 per batch row; sums the 4 N-slice partials first.
// ---------------------------------------------------------------------------
__global__ __launch_bounds__(256) void softmax_rows(const float* __restrict__ part,
                                                    float* __restrict__ out) {
    const int b = blockIdx.x;
    const int tid  = threadIdx.x;
    const int lane = tid & 63;
    const int wv   = tid >> 6;
    __shared__ float sred[4];
    __shared__ float ssum[4];
    float x[8];
    float mx = -3.4e38f;
#pragma unroll
    for (int j = 0; j < 8; ++j) {
        int flat = (tid + j * 256) * 32 + b;              // row = s*32 + b
        float v = part[flat] + part[MROWS + flat]
                + part[2 * MROWS + flat] + part[3 * MROWS + flat];
        x[j] = v;
        mx = fmaxf(mx, v);
    }
#pragma unroll
    for (int o = 1; o < 64; o <<= 1) mx = fmaxf(mx, __shfl_xor(mx, o));
    if (lane == 0) sred[wv] = mx;
    __syncthreads();
    mx = fmaxf(fmaxf(sred[0], sred[1]), fmaxf(sred[2], sred[3]));
    float s = 0.f;
#pragma unroll
    for (int j = 0; j < 8; ++j) { x[j] = __expf(x[j] - mx); s += x[j]; }
#pragma unroll
    for (int o = 1; o < 64; o <<= 1) s += __shfl_xor(s, o);
    if (lane == 0) ssum[wv] = s;
    __syncthreads();
    s = ssum[0] + ssum[1] + ssum[2] + ssum[3];
    float inv = 1.f / s;
#pragma unroll
    for (int j = 0; j < 8; ++j) out[(size_t)b * SEQ + tid + j * 256] = x[j] * inv;
}

extern "C" void kernel_launch(void* const* d_in, const int* in_sizes, int n_in,
                              void* d_out, int out_size, void* d_ws, size_t ws_size,
                              hipStream_t stream) {
    const float* hidden = (const float*)d_in[0];   // [32][1024]
    const float* enc    = (const float*)d_in[1];   // [2048][32][1024]
    const float* attn_w = (const float*)d_in[2];   // [2048][1024]
    const float* attn_b = (const float*)d_in[3];   // [1024]
    const float* v      = (const float*)d_in[4];   // [1024]
    float* out = (float*)d_out;                    // [32][2048]

    f16*   wt   = (f16*)d_ws;                            // 2 MB tiled We
    float* hb   = (float*)((char*)d_ws + 2097152);       // 128 KB
    float* part = (float*)((char*)d_ws + 2097152 + 131072); // 1 MB N-partials

    prep_w<<<512, 256, 0, stream>>>(attn_w, wt);
    prep_hb<<<128, 256, 0, stream>>>(hidden, attn_w, attn_b, hb);
    fused_energy<<<1024, 512, 0, stream>>>(enc, wt, hb, v, part);
    softmax_rows<<<32, 256, 0, stream>>>(part, out);
}

// Round 8
// 291.923 us; speedup vs baseline: 1.4735x; 1.0732x over previous
//
#include <hip/hip_runtime.h>

// Bahdanau attention fused kernel for MI355X (gfx950).
// scores[b][s] = softmax_s( v . tanh( hb[b,:] + enc[s,b,:] @ We ) )
// R7: m201-style 8-phase schedule. BM=256,BN=256,BK=64; 4 phases/K-tile,
//     counted vmcnt ledger (P0:10, P2:8, P3:2 — never 0 mid-loop),
//     B via global_load_lds (pre-swizzled wt), A reg-staged f32->f16 with
//     issue-early/convert-late (T14). One barrier per phase. setprio (T5).

typedef _Float16 f16;
typedef _Float16 half8 __attribute__((ext_vector_type(8)));
typedef float f32x4 __attribute__((ext_vector_type(4)));

#define KDIM 1024
#define SEQ  2048
#define MROWS 65536

typedef __attribute__((address_space(1))) void gvoid;
typedef __attribute__((address_space(3))) void svoid;

__device__ __forceinline__ void gload_lds16(const void* g, void* l) {
    __builtin_amdgcn_global_load_lds((const gvoid*)g, (svoid*)l, 16, 0, 0);
}

// ---------------------------------------------------------------------------
// prep_w: transpose + f16-convert enc-half of attn_w into subtile images.
// Subtile id tk = ((nq*16 + t)*2 + kk): [256 n][32 k] LDS image, 16B block
// p = nloc*4 + ((kblk + (nloc>>1)) & 3); payload k = 1024 + t*64 + kk*32 + kblk*8 + j.
// ---------------------------------------------------------------------------
__global__ __launch_bounds__(256) void prep_w(const float* __restrict__ w,
                                              f16* __restrict__ wt) {
    int idx  = blockIdx.x * 256 + threadIdx.x;   // 0..131071
    int kblk = idx & 3;
    int nloc = (idx >> 2) & 255;
    int tk   = idx >> 10;                        // 0..127
    int kk = tk & 1, tt = (tk >> 1) & 15, nq = tk >> 5;
    int n_g = nq * 256 + nloc;
    int kb  = 1024 + tt * 64 + kk * 32 + kblk * 8;
    half8 h;
#pragma unroll
    for (int j = 0; j < 8; ++j)
        h[j] = (f16)w[(size_t)(kb + j) * 1024 + n_g];
    int p = nloc * 4 + ((kblk + (nloc >> 1)) & 3);
    *(half8*)&wt[(size_t)tk * 8192 + p * 8] = h;
}

// ---------------------------------------------------------------------------
// prep_hb: hb[b][n] = attn_b[n] + sum_k hidden[b][k] * attn_w[k][n]  (f32)
// ---------------------------------------------------------------------------
__global__ __launch_bounds__(256) void prep_hb(const float* __restrict__ hidden,
                                               const float* __restrict__ attn_w,
                                               const float* __restrict__ attn_b,
                                               float* __restrict__ hb) {
    int b = blockIdx.x >> 2;
    int n = (blockIdx.x & 3) * 256 + threadIdx.x;
    const float* h = hidden + (size_t)b * 1024;
    float acc = attn_b[n];
#pragma unroll 8
    for (int k = 0; k < 1024; ++k)
        acc += h[k] * attn_w[(size_t)k * 1024 + n];
    hb[(size_t)b * 1024 + n] = acc;
}

// ---------------------------------------------------------------------------
// fused_energy: 256 rows x 256 N-slice per block; K = 16 tiles of BK=64.
// 8 waves 2Mx4N, wave tile 128x64, frags 8(M)x4(N), 64 MFMA / wave / K-tile
// in 4 phases of 16 (kk x mi-half quadrants).
// ---------------------------------------------------------------------------
__global__ __launch_bounds__(512, 2)
void fused_energy(const float* __restrict__ enc, const f16* __restrict__ wt,
                  const float* __restrict__ hb, const float* __restrict__ vvec,
                  float* __restrict__ partout) {
    __shared__ f16 Bls[2][2][8192];   // [parity][kk] 16 KB subtiles
    __shared__ f16 Als[2][2][8192];
    __shared__ float red[4][256];

    const int tid  = threadIdx.x;
    const int lane = tid & 63;
    const int wv   = tid >> 6;          // 0..7
    const int wm   = wv >> 2;           // 0..1
    const int wn   = wv & 3;            // 0..3
    const int l15  = lane & 15;
    const int l4   = lane >> 4;

    // XCD-bijective mapping: xcd owns 32 consecutive row-tiles; same-row quads co-XCD
    const int bid   = blockIdx.x;       // 0..1023
    const int xcd   = bid & 7;
    const int chunk = bid >> 3;
    const int mt    = xcd * 32 + (chunk >> 2);
    const int nq    = chunk & 3;
    const int mrow0 = mt * 256;
    const int ncol0 = nq * 256;

    const char* wtNq = (const char*)wt + (size_t)nq * 16 * 2 * 16384;
    const int stOff  = wv * 2048 + lane * 16;

    // A reg staging: thread -> row arow, k-half akh (16 f32 per kk subtile)
    const int arow = tid >> 1;
    const int akh  = tid & 1;
    const float* aG = enc + (size_t)(mrow0 + arow) * KDIM + akh * 16;
    const int pw0 = arow * 4 + ((akh * 2     + (arow >> 1)) & 3);
    const int pw1 = arow * 4 + ((akh * 2 + 1 + (arow >> 1)) & 3);

    int aOffB[8], bOffB[4];
#pragma unroll
    for (int mi = 0; mi < 8; ++mi) {
        int r = wm * 128 + mi * 16 + l15;
        aOffB[mi] = (r * 4 + ((l4 + (r >> 1)) & 3)) * 16;
    }
#pragma unroll
    for (int nj = 0; nj < 4; ++nj) {
        int n = wn * 64 + nj * 16 + l15;
        bOffB[nj] = (n * 4 + ((l4 + (n >> 1)) & 3)) * 16;
    }

    const f32x4 zero = {0.f, 0.f, 0.f, 0.f};
    f32x4 acc[8][4];
#pragma unroll
    for (int mi = 0; mi < 8; ++mi)
#pragma unroll
        for (int nj = 0; nj < 4; ++nj) acc[mi][nj] = zero;

    f32x4 rA0[4], rA1[4];
    half8 bf[4], af[4];

#define WAITV(N) asm volatile("s_waitcnt vmcnt(" #N ")" ::: "memory")
#define LGKM0    asm volatile("s_waitcnt lgkmcnt(0)" ::: "memory")
#define BAR      __builtin_amdgcn_s_barrier()
#define PRIO1    __builtin_amdgcn_s_setprio(1)
#define PRIO0    __builtin_amdgcn_s_setprio(0)

#define STAGE_B(T, KK)                                                        \
    {                                                                         \
        const char* s_ = wtNq + (size_t)((T) * 2 + (KK)) * 16384 + stOff;     \
        char* d_ = (char*)Bls + (((T) & 1) * 32768) + (KK) * 16384 + stOff;   \
        gload_lds16(s_, d_);                                                  \
        gload_lds16(s_ + 1024, d_ + 1024);                                    \
    }
#define LOADA(T, KK, R)                                                       \
    {                                                                         \
        const float* p_ = aG + (T) * 64 + (KK) * 32;                          \
        R[0] = *(const f32x4*)(p_);      R[1] = *(const f32x4*)(p_ + 4);      \
        R[2] = *(const f32x4*)(p_ + 8);  R[3] = *(const f32x4*)(p_ + 12);     \
    }
#define CVTA(PB, KK, R)                                                       \
    {                                                                         \
        half8 h0_, h1_;                                                       \
        _Pragma("unroll") for (int j = 0; j < 4; ++j) {                       \
            h0_[j] = (f16)R[0][j]; h0_[4 + j] = (f16)R[1][j];                 \
            h1_[j] = (f16)R[2][j]; h1_[4 + j] = (f16)R[3][j];                 \
        }                                                                     \
        char* d_ = (char*)Als + (PB) * 32768 + (KK) * 16384;                  \
        *(half8*)(d_ + pw0 * 16) = h0_;                                       \
        *(half8*)(d_ + pw1 * 16) = h1_;                                       \
    }
#define READB(PC, KK)                                                         \
    _Pragma("unroll") for (int nj = 0; nj < 4; ++nj)                          \
        bf[nj] = *(const half8*)((char*)Bls + (PC) * 32768 + (KK) * 16384 + bOffB[nj]);
#define READA(PC, KK, MH)                                                     \
    _Pragma("unroll") for (int i = 0; i < 4; ++i)                             \
        af[i] = *(const half8*)((char*)Als + (PC) * 32768 + (KK) * 16384 + aOffB[(MH) * 4 + i]);
#define MFMA16(MH)                                                            \
    PRIO1;                                                                    \
    _Pragma("unroll") for (int i = 0; i < 4; ++i)                             \
        _Pragma("unroll") for (int nj = 0; nj < 4; ++nj)                      \
            acc[(MH) * 4 + i][nj] = __builtin_amdgcn_mfma_f32_16x16x32_f16(   \
                af[i], bf[nj], acc[(MH) * 4 + i][nj], 0, 0, 0);               \
    PRIO0;

    // ---- prologue: tile 0 fully staged; A(1) regs in flight ----
    STAGE_B(0, 0); STAGE_B(0, 1);
    LOADA(0, 0, rA0); LOADA(0, 1, rA1);
    WAITV(4);                // B(0) + A(0)kk0 landed
    CVTA(0, 0, rA0);
    WAITV(0);                // A(0)kk1 landed
    CVTA(0, 1, rA1);
    LOADA(1, 0, rA0); LOADA(1, 1, rA1);   // 8 ops in flight
    LGKM0; BAR;

    // ---- steady loop: t = 0..13 ----
    for (int t = 0; t < 14; ++t) {
        const int cur = t & 1, nxt = cur ^ 1;
        // P0 (kk0, mi 0-3)
        STAGE_B(t + 1, 0);
        WAITV(10);                       // drains B(t)kk1 for P1 (cross-wave via barrier)
        READB(cur, 0); READA(cur, 0, 0);
        MFMA16(0);
        BAR;
        // P1 (kk0, mi 4-7)
        STAGE_B(t + 1, 1);
        READA(cur, 0, 1);
        MFMA16(1);
        BAR;
        // P2 (kk1, mi 0-3)
        WAITV(8);                        // drains A(t+1)kk0 regs
        CVTA(nxt, 0, rA0);
        LOADA(t + 2, 0, rA0);
        READB(cur, 1); READA(cur, 1, 0);
        MFMA16(0);
        LGKM0; BAR;
        // P3 (kk1, mi 4-7)
        WAITV(2);                        // drains A(t+1)kk1 regs + B(t+1)kk0
        CVTA(nxt, 1, rA1);
        LOADA(t + 2, 1, rA1);
        READA(cur, 1, 1);
        MFMA16(1);
        LGKM0; BAR;
    }
    // ---- t = 14 (no new A issues) ----
    {
        const int cur = 0, nxt = 1;
        STAGE_B(15, 0);
        WAITV(10);
        READB(cur, 0); READA(cur, 0, 0);
        MFMA16(0);
        BAR;
        STAGE_B(15, 1);
        READA(cur, 0, 1);
        MFMA16(1);
        BAR;
        WAITV(8);
        CVTA(nxt, 0, rA0);
        READB(cur, 1); READA(cur, 1, 0);
        MFMA16(0);
        LGKM0; BAR;
        WAITV(2);
        CVTA(nxt, 1, rA1);
        READA(cur, 1, 1);
        MFMA16(1);
        LGKM0; BAR;
    }
    // ---- t = 15 (drain) ----
    {
        const int cur = 1;
        WAITV(0);
        READB(cur, 0); READA(cur, 0, 0);
        MFMA16(0);
        BAR;
        READA(cur, 0, 1);
        MFMA16(1);
        BAR;
        READB(cur, 1); READA(cur, 1, 0);
        MFMA16(0);
        BAR;
        READA(cur, 1, 1);
        MFMA16(1);
    }

#undef STAGE_B
#undef LOADA
#undef CVTA
#undef READB
#undef READA
#undef MFMA16

    // ---- epilogue: e = acc + hb -> tanh -> * v, partial over this N slice ----
    float vv[4];
#pragma unroll
    for (int nj = 0; nj < 4; ++nj) vv[nj] = vvec[ncol0 + wn * 64 + nj * 16 + l15];
#pragma unroll
    for (int mi = 0; mi < 8; ++mi) {
#pragma unroll
        for (int rg = 0; rg < 4; ++rg) {
            int rl = wm * 128 + mi * 16 + l4 * 4 + rg;    // local row 0..255
            const float* hbrow = hb + (size_t)((mrow0 + rl) & 31) * 1024
                                 + ncol0 + wn * 64 + l15;
            float sum = 0.f;
#pragma unroll
            for (int nj = 0; nj < 4; ++nj) {
                float e  = acc[mi][nj][rg] + hbrow[nj * 16];
                float e2 = __expf(2.f * e);
                sum += (1.f - 2.f / (e2 + 1.f)) * vv[nj];  // tanh(e) * v
            }
            float p = sum;
            p += __shfl_xor(p, 1);
            p += __shfl_xor(p, 2);
            p += __shfl_xor(p, 4);
            p += __shfl_xor(p, 8);
            if (l15 == 0) red[wn][rl] = p;
        }
    }
    __syncthreads();
    if (tid < 256) {
        float s = red[0][tid] + red[1][tid] + red[2][tid] + red[3][tid];
        partout[(size_t)nq * MROWS + mrow0 + tid] = s;
    }
}

// ---------------------------------------------------------------------------
// softmax over S=2048 per batch row; sums the 4 N-slice partials first.
// ---------------------------------------------------------------------------
__global__ __launch_bounds__(256) void softmax_rows(const float* __restrict__ part,
                                                    float* __restrict__ out) {
    const int b = blockIdx.x;
    const int tid  = threadIdx.x;
    const int lane = tid & 63;
    const int wv   = tid >> 6;
    __shared__ float sred[4];
    __shared__ float ssum[4];
    float x[8];
    float mx = -3.4e38f;
#pragma unroll
    for (int j = 0; j < 8; ++j) {
        int flat = (tid + j * 256) * 32 + b;              // row = s*32 + b
        float v = part[flat] + part[MROWS + flat]
                + part[2 * MROWS + flat] + part[3 * MROWS + flat];
        x[j] = v;
        mx = fmaxf(mx, v);
    }
#pragma unroll
    for (int o = 1; o < 64; o <<= 1) mx = fmaxf(mx, __shfl_xor(mx, o));
    if (lane == 0) sred[wv] = mx;
    __syncthreads();
    mx = fmaxf(fmaxf(sred[0], sred[1]), fmaxf(sred[2], sred[3]));
    float s = 0.f;
#pragma unroll
    for (int j = 0; j < 8; ++j) { x[j] = __expf(x[j] - mx); s += x[j]; }
#pragma unroll
    for (int o = 1; o < 64; o <<= 1) s += __shfl_xor(s, o);
    if (lane == 0) ssum[wv] = s;
    __syncthreads();
    s = ssum[0] + ssum[1] + ssum[2] + ssum[3];
    float inv = 1.f / s;
#pragma unroll
    for (int j = 0; j < 8; ++j) out[(size_t)b * SEQ + tid + j * 256] = x[j] * inv;
}

extern "C" void kernel_launch(void* const* d_in, const int* in_sizes, int n_in,
                              void* d_out, int out_size, void* d_ws, size_t ws_size,
                              hipStream_t stream) {
    const float* hidden = (const float*)d_in[0];   // [32][1024]
    const float* enc    = (const float*)d_in[1];   // [2048][32][1024]
    const float* attn_w = (const float*)d_in[2];   // [2048][1024]
    const float* attn_b = (const float*)d_in[3];   // [1024]
    const float* v      = (const float*)d_in[4];   // [1024]
    float* out = (float*)d_out;                    // [32][2048]

    f16*   wt   = (f16*)d_ws;                            // 2 MB tiled We
    float* hb   = (float*)((char*)d_ws + 2097152);       // 128 KB
    float* part = (float*)((char*)d_ws + 2097152 + 131072); // 1 MB N-partials

    prep_w<<<512, 256, 0, stream>>>(attn_w, wt);
    prep_hb<<<128, 256, 0, stream>>>(hidden, attn_w, attn_b, hb);
    fused_energy<<<1024, 512, 0, stream>>>(enc, wt, hb, v, part);
    softmax_rows<<<32, 256, 0, stream>>>(part, out);
}

// Round 10
// 261.817 us; speedup vs baseline: 1.6430x; 1.1150x over previous
//
#include <hip/hip_runtime.h>

// Bahdanau attention fused kernel for MI355X (gfx950).
// scores[b][s] = softmax_s( v . tanh( hb[b,:] + enc[s,b,:] @ We ) )
// R8: R7's 4-phase schedule with the vmcnt ledger FIXED so no wait targets an
//     op younger than 2 phases (A-loads get 4-phase windows). Stage both B
//     halves in P0; waits: P0 none, P1 none, P2 vmcnt(8), P3 vmcnt(4).

typedef _Float16 f16;
typedef _Float16 half8 __attribute__((ext_vector_type(8)));
typedef float f32x4 __attribute__((ext_vector_type(4)));

#define KDIM 1024
#define SEQ  2048
#define MROWS 65536

typedef __attribute__((address_space(1))) void gvoid;
typedef __attribute__((address_space(3))) void svoid;

__device__ __forceinline__ void gload_lds16(const void* g, void* l) {
    __builtin_amdgcn_global_load_lds((const gvoid*)g, (svoid*)l, 16, 0, 0);
}

// ---------------------------------------------------------------------------
// prep_w: transpose + f16-convert enc-half of attn_w into subtile images.
// Subtile id tk = ((nq*16 + t)*2 + kk): [256 n][32 k] LDS image, 16B block
// p = nloc*4 + ((kblk + (nloc>>1)) & 3); payload k = 1024 + t*64 + kk*32 + kblk*8 + j.
// ---------------------------------------------------------------------------
__global__ __launch_bounds__(256) void prep_w(const float* __restrict__ w,
                                              f16* __restrict__ wt) {
    int idx  = blockIdx.x * 256 + threadIdx.x;   // 0..131071
    int kblk = idx & 3;
    int nloc = (idx >> 2) & 255;
    int tk   = idx >> 10;                        // 0..127
    int kk = tk & 1, tt = (tk >> 1) & 15, nq = tk >> 5;
    int n_g = nq * 256 + nloc;
    int kb  = 1024 + tt * 64 + kk * 32 + kblk * 8;
    half8 h;
#pragma unroll
    for (int j = 0; j < 8; ++j)
        h[j] = (f16)w[(size_t)(kb + j) * 1024 + n_g];
    int p = nloc * 4 + ((kblk + (nloc >> 1)) & 3);
    *(half8*)&wt[(size_t)tk * 8192 + p * 8] = h;
}

// ---------------------------------------------------------------------------
// prep_hb: hb[b][n] = attn_b[n] + sum_k hidden[b][k] * attn_w[k][n]  (f32)
// ---------------------------------------------------------------------------
__global__ __launch_bounds__(256) void prep_hb(const float* __restrict__ hidden,
                                               const float* __restrict__ attn_w,
                                               const float* __restrict__ attn_b,
                                               float* __restrict__ hb) {
    int b = blockIdx.x >> 2;
    int n = (blockIdx.x & 3) * 256 + threadIdx.x;
    const float* h = hidden + (size_t)b * 1024;
    float acc = attn_b[n];
#pragma unroll 8
    for (int k = 0; k < 1024; ++k)
        acc += h[k] * attn_w[(size_t)k * 1024 + n];
    hb[(size_t)b * 1024 + n] = acc;
}

// ---------------------------------------------------------------------------
// fused_energy: 256 rows x 256 N-slice per block; K = 16 tiles of BK=64.
// 8 waves 2Mx4N, wave tile 128x64, frags 8(M)x4(N), 64 MFMA / wave / K-tile
// in 4 phases of 16. Steady-state FIFO (12 ops/tile): P0 issues B(t+1)x4,
// P2 issues A(t+2,0)x4 after vmcnt(8), P3 issues A(t+2,1)x4 after vmcnt(4).
// ---------------------------------------------------------------------------
__global__ __launch_bounds__(512, 2)
void fused_energy(const float* __restrict__ enc, const f16* __restrict__ wt,
                  const float* __restrict__ hb, const float* __restrict__ vvec,
                  float* __restrict__ partout) {
    __shared__ f16 Bls[2][2][8192];   // [parity][kk] 16 KB subtiles
    __shared__ f16 Als[2][2][8192];
    __shared__ float red[4][256];

    const int tid  = threadIdx.x;
    const int lane = tid & 63;
    const int wv   = tid >> 6;          // 0..7
    const int wm   = wv >> 2;           // 0..1
    const int wn   = wv & 3;            // 0..3
    const int l15  = lane & 15;
    const int l4   = lane >> 4;

    // XCD-bijective mapping: xcd owns 32 consecutive row-tiles; same-row quads co-XCD
    const int bid   = blockIdx.x;       // 0..1023
    const int xcd   = bid & 7;
    const int chunk = bid >> 3;
    const int mt    = xcd * 32 + (chunk >> 2);
    const int nq    = chunk & 3;
    const int mrow0 = mt * 256;
    const int ncol0 = nq * 256;

    const char* wtNq = (const char*)wt + (size_t)nq * 16 * 2 * 16384;
    const int stOff  = wv * 2048 + lane * 16;

    // A reg staging: thread -> row arow, k-half akh (16 f32 per kk subtile)
    const int arow = tid >> 1;
    const int akh  = tid & 1;
    const float* aG = enc + (size_t)(mrow0 + arow) * KDIM + akh * 16;
    const int pw0 = arow * 4 + ((akh * 2     + (arow >> 1)) & 3);
    const int pw1 = arow * 4 + ((akh * 2 + 1 + (arow >> 1)) & 3);

    int aOffB[8], bOffB[4];
#pragma unroll
    for (int mi = 0; mi < 8; ++mi) {
        int r = wm * 128 + mi * 16 + l15;
        aOffB[mi] = (r * 4 + ((l4 + (r >> 1)) & 3)) * 16;
    }
#pragma unroll
    for (int nj = 0; nj < 4; ++nj) {
        int n = wn * 64 + nj * 16 + l15;
        bOffB[nj] = (n * 4 + ((l4 + (n >> 1)) & 3)) * 16;
    }

    const f32x4 zero = {0.f, 0.f, 0.f, 0.f};
    f32x4 acc[8][4];
#pragma unroll
    for (int mi = 0; mi < 8; ++mi)
#pragma unroll
        for (int nj = 0; nj < 4; ++nj) acc[mi][nj] = zero;

    f32x4 rA0[4], rA1[4];
    half8 bf[4], af[4];

#define WAITV(N) asm volatile("s_waitcnt vmcnt(" #N ")" ::: "memory")
#define LGKM0    asm volatile("s_waitcnt lgkmcnt(0)" ::: "memory")
#define BAR      __builtin_amdgcn_s_barrier()
#define PRIO1    __builtin_amdgcn_s_setprio(1)
#define PRIO0    __builtin_amdgcn_s_setprio(0)

#define STAGE_B(T, KK)                                                        \
    {                                                                         \
        const char* s_ = wtNq + (size_t)((T) * 2 + (KK)) * 16384 + stOff;     \
        char* d_ = (char*)Bls + (((T) & 1) * 32768) + (KK) * 16384 + stOff;   \
        gload_lds16(s_, d_);                                                  \
        gload_lds16(s_ + 1024, d_ + 1024);                                    \
    }
#define LOADA(T, KK, R)                                                       \
    {                                                                         \
        const float* p_ = aG + (T) * 64 + (KK) * 32;                          \
        R[0] = *(const f32x4*)(p_);      R[1] = *(const f32x4*)(p_ + 4);      \
        R[2] = *(const f32x4*)(p_ + 8);  R[3] = *(const f32x4*)(p_ + 12);     \
    }
#define CVTA(PB, KK, R)                                                       \
    {                                                                         \
        half8 h0_, h1_;                                                       \
        _Pragma("unroll") for (int j = 0; j < 4; ++j) {                       \
            h0_[j] = (f16)R[0][j]; h0_[4 + j] = (f16)R[1][j];                 \
            h1_[j] = (f16)R[2][j]; h1_[4 + j] = (f16)R[3][j];                 \
        }                                                                     \
        char* d_ = (char*)Als + (PB) * 32768 + (KK) * 16384;                  \
        *(half8*)(d_ + pw0 * 16) = h0_;                                       \
        *(half8*)(d_ + pw1 * 16) = h1_;                                       \
    }
#define READB(PC, KK)                                                         \
    _Pragma("unroll") for (int nj = 0; nj < 4; ++nj)                          \
        bf[nj] = *(const half8*)((char*)Bls + (PC) * 32768 + (KK) * 16384 + bOffB[nj]);
#define READA(PC, KK, MH)                                                     \
    _Pragma("unroll") for (int i = 0; i < 4; ++i)                             \
        af[i] = *(const half8*)((char*)Als + (PC) * 32768 + (KK) * 16384 + aOffB[(MH) * 4 + i]);
#define MFMA16(MH)                                                            \
    PRIO1;                                                                    \
    _Pragma("unroll") for (int i = 0; i < 4; ++i)                             \
        _Pragma("unroll") for (int nj = 0; nj < 4; ++nj)                      \
            acc[(MH) * 4 + i][nj] = __builtin_amdgcn_mfma_f32_16x16x32_f16(   \
                af[i], bf[nj], acc[(MH) * 4 + i][nj], 0, 0, 0);               \
    PRIO0;

    // ---- prologue: tile 0 staged + converted; A(1) regs in flight (8 ops) ----
    STAGE_B(0, 0); STAGE_B(0, 1);          // 4 ops
    LOADA(0, 0, rA0); LOADA(0, 1, rA1);    // +8 = 12
    WAITV(4);                // B(0)x4 + A(0,0)x4 retired
    CVTA(0, 0, rA0);
    WAITV(0);                // A(0,1) retired
    CVTA(0, 1, rA1);
    LOADA(1, 0, rA0); LOADA(1, 1, rA1);    // 8 in flight
    LGKM0; BAR;

    // ---- steady loop: t = 0..13 ----
    // FIFO at P2 wait: [A(t+1,0)x4, A(t+1,1)x4, B(t+1)x4] = 12 -> vmcnt(8)
    // FIFO at P3 wait: [A(t+1,1)x4, B(t+1)x4, A(t+2,0)x4] = 12 -> vmcnt(4)
    for (int t = 0; t < 14; ++t) {
        const int cur = t & 1, nxt = cur ^ 1;
        // P0 (kk0, mi 0-3): stage both B halves of t+1
        STAGE_B(t + 1, 0); STAGE_B(t + 1, 1);
        READB(cur, 0); READA(cur, 0, 0);
        MFMA16(0);
        BAR;
        // P1 (kk0, mi 4-7)
        READA(cur, 0, 1);
        MFMA16(1);
        BAR;
        // P2 (kk1, mi 0-3): A(t+1,0) regs ready 4 phases after issue
        WAITV(8);
        CVTA(nxt, 0, rA0);
        LOADA(t + 2, 0, rA0);
        READB(cur, 1); READA(cur, 1, 0);
        MFMA16(0);
        LGKM0; BAR;
        // P3 (kk1, mi 4-7): A(t+1,1) regs + B(t+1) LDS retired before barrier
        WAITV(4);
        CVTA(nxt, 1, rA1);
        LOADA(t + 2, 1, rA1);
        READA(cur, 1, 1);
        MFMA16(1);
        LGKM0; BAR;
    }
    // ---- t = 14 (no t+2 loads) ----
    {
        const int cur = 0, nxt = 1;
        STAGE_B(15, 0); STAGE_B(15, 1);
        READB(cur, 0); READA(cur, 0, 0);
        MFMA16(0);
        BAR;
        READA(cur, 0, 1);
        MFMA16(1);
        BAR;
        WAITV(8);                       // drains A(15,0)
        CVTA(nxt, 0, rA0);
        READB(cur, 1); READA(cur, 1, 0);
        MFMA16(0);
        LGKM0; BAR;
        WAITV(0);                       // drains A(15,1) + B(15)
        CVTA(nxt, 1, rA1);
        READA(cur, 1, 1);
        MFMA16(1);
        LGKM0; BAR;
    }
    // ---- t = 15 (pure compute, everything resident) ----
    {
        const int cur = 1;
        READB(cur, 0); READA(cur, 0, 0);
        MFMA16(0);
        READA(cur, 0, 1);
        MFMA16(1);
        READB(cur, 1); READA(cur, 1, 0);
        MFMA16(0);
        READA(cur, 1, 1);
        MFMA16(1);
    }

#undef STAGE_B
#undef LOADA
#undef CVTA
#undef READB
#undef READA
#undef MFMA16

    // ---- epilogue: e = acc + hb -> tanh -> * v, partial over this N slice ----
    float vv[4];
#pragma unroll
    for (int nj = 0; nj < 4; ++nj) vv[nj] = vvec[ncol0 + wn * 64 + nj * 16 + l15];
#pragma unroll
    for (int mi = 0; mi < 8; ++mi) {
#pragma unroll
        for (int rg = 0; rg < 4; ++rg) {
            int rl = wm * 128 + mi * 16 + l4 * 4 + rg;    // local row 0..255
            const float* hbrow = hb + (size_t)((mrow0 + rl) & 31) * 1024
                                 + ncol0 + wn * 64 + l15;
            float sum = 0.f;
#pragma unroll
            for (int nj = 0; nj < 4; ++nj) {
                float e  = acc[mi][nj][rg] + hbrow[nj * 16];
                float e2 = __expf(2.f * e);
                sum += (1.f - 2.f / (e2 + 1.f)) * vv[nj];  // tanh(e) * v
            }
            float p = sum;
            p += __shfl_xor(p, 1);
            p += __shfl_xor(p, 2);
            p += __shfl_xor(p, 4);
            p += __shfl_xor(p, 8);
            if (l15 == 0) red[wn][rl] = p;
        }
    }
    __syncthreads();
    if (tid < 256) {
        float s = red[0][tid] + red[1][tid] + red[2][tid] + red[3][tid];
        partout[(size_t)nq * MROWS + mrow0 + tid] = s;
    }
}

// ---------------------------------------------------------------------------
// softmax over S=2048 per batch row; sums the 4 N-slice partials first.
// ---------------------------------------------------------------------------
__global__ __launch_bounds__(256) void softmax_rows(const float* __restrict__ part,
                                                    float* __restrict__ out) {
    const int b = blockIdx.x;
    const int tid  = threadIdx.x;
    const int lane = tid & 63;
    const int wv   = tid >> 6;
    __shared__ float sred[4];
    __shared__ float ssum[4];
    float x[8];
    float mx = -3.4e38f;
#pragma unroll
    for (int j = 0; j < 8; ++j) {
        int flat = (tid + j * 256) * 32 + b;              // row = s*32 + b
        float v = part[flat] + part[MROWS + flat]
                + part[2 * MROWS + flat] + part[3 * MROWS + flat];
        x[j] = v;
        mx = fmaxf(mx, v);
    }
#pragma unroll
    for (int o = 1; o < 64; o <<= 1) mx = fmaxf(mx, __shfl_xor(mx, o));
    if (lane == 0) sred[wv] = mx;
    __syncthreads();
    mx = fmaxf(fmaxf(sred[0], sred[1]), fmaxf(sred[2], sred[3]));
    float s = 0.f;
#pragma unroll
    for (int j = 0; j < 8; ++j) { x[j] = __expf(x[j] - mx); s += x[j]; }
#pragma unroll
    for (int o = 1; o < 64; o <<= 1) s += __shfl_xor(s, o);
    if (lane == 0) ssum[wv] = s;
    __syncthreads();
    s = ssum[0] + ssum[1] + ssum[2] + ssum[3];
    float inv = 1.f / s;
#pragma unroll
    for (int j = 0; j < 8; ++j) out[(size_t)b * SEQ + tid + j * 256] = x[j] * inv;
}

extern "C" void kernel_launch(void* const* d_in, const int* in_sizes, int n_in,
                              void* d_out, int out_size, void* d_ws, size_t ws_size,
                              hipStream_t stream) {
    const float* hidden = (const float*)d_in[0];   // [32][1024]
    const float* enc    = (const float*)d_in[1];   // [2048][32][1024]
    const float* attn_w = (const float*)d_in[2];   // [2048][1024]
    const float* attn_b = (const float*)d_in[3];   // [1024]
    const float* v      = (const float*)d_in[4];   // [1024]
    float* out = (float*)d_out;                    // [32][2048]

    f16*   wt   = (f16*)d_ws;                            // 2 MB tiled We
    float* hb   = (float*)((char*)d_ws + 2097152);       // 128 KB
    float* part = (float*)((char*)d_ws + 2097152 + 131072); // 1 MB N-partials

    prep_w<<<512, 256, 0, stream>>>(attn_w, wt);
    prep_hb<<<128, 256, 0, stream>>>(hidden, attn_w, attn_b, hb);
    fused_energy<<<1024, 512, 0, stream>>>(enc, wt, hb, v, part);
    softmax_rows<<<32, 256, 0, stream>>>(part, out);
}